// Round 8
// baseline (2534.520 us; speedup 1.0000x reference)
//
#include <hip/hip_runtime.h>
#include <hip/hip_bf16.h>
#include <cstdint>

// ---------------------------------------------------------------------------
// B=2 S=2048 D=512 H=8 HD=64, FFH=1024. Encoder: 4 layers, G=2, Sg=2048
// (block-causal-64 AND doc mask). Router: 2 layers, G=64, Sg=72, full attn.
// Round 8: GEMMs were latency-bound (MfmaUtil 13%, Occ 16%). (1) producers
// emit bf16 hi/lo for A (no f32->bf16 VALU in K-loop, half A traffic);
// (2) split-K=4 + fp32 atomicAdd for N=512 GEMMs (128->512 blocks).
// ---------------------------------------------------------------------------

typedef __attribute__((ext_vector_type(8))) short short8;   // 8 bf16 = 4 VGPR
typedef __attribute__((ext_vector_type(4))) float f32x4;
typedef unsigned short ushort_t;

__device__ __forceinline__ float bf2f(unsigned short u) {
    return __uint_as_float(((unsigned)u) << 16);
}
__device__ __forceinline__ unsigned short f2bf(float f) {
    unsigned u = __float_as_uint(f);
    unsigned r = 0x7FFFu + ((u >> 16) & 1u);
    return (unsigned short)((u + r) >> 16);
}
__device__ __forceinline__ float wave_sum64(float v) {
#pragma unroll
    for (int o = 32; o; o >>= 1) v += __shfl_xor(v, o);
    return v;
}

#define MFMA16(a, b, c) __builtin_amdgcn_mfma_f32_16x16x32_bf16(a, b, c, 0, 0, 0)

// ---- f32 copy (input x -> mutable X) --------------------------------------
__global__ void copy_in_kernel(const float* __restrict__ src,
                               float* __restrict__ dst, int n) {
    int i = blockIdx.x * 256 + threadIdx.x;
    if (i < n) dst[i] = src[i];
}

// ---- weight transpose + hi/lo bf16 split: W[K,N] -> WT_hi/lo[N,K] ---------
__global__ __launch_bounds__(256) void wsplit_kernel(const float* __restrict__ W,
        unsigned short* __restrict__ WH, unsigned short* __restrict__ WL,
        int K, int N) {
    __shared__ float tile[32][33];
    int bn = blockIdx.x * 32, bk = blockIdx.y * 32;
    int tx = threadIdx.x & 31, ty = threadIdx.x >> 5;
#pragma unroll
    for (int i = 0; i < 4; ++i)
        tile[ty + 8 * i][tx] = W[(size_t)(bk + ty + 8 * i) * N + bn + tx];
    __syncthreads();
#pragma unroll
    for (int i = 0; i < 4; ++i) {
        int n = bn + ty + 8 * i, k = bk + tx;
        float x = tile[tx][ty + 8 * i];
        unsigned short h = f2bf(x);
        unsigned short lo = f2bf(x - bf2f(h));
        WH[(size_t)n * K + k] = h;
        WL[(size_t)n * K + k] = lo;
    }
}

// ---- RMSNorm over D=512, emits bf16 hi/lo ---------------------------------
__global__ __launch_bounds__(256) void rmsnorm_kernel(const float* __restrict__ X,
        const float* __restrict__ W, ushort_t* __restrict__ XNH,
        ushort_t* __restrict__ XNL) {
    int t = blockIdx.x, tid = threadIdx.x;
    const float* xr = X + (size_t)t * 512;
    float v0 = xr[tid], v1 = xr[tid + 256];
    float ss = wave_sum64(v0 * v0 + v1 * v1);
    __shared__ float red[4];
    if ((tid & 63) == 0) red[tid >> 6] = ss;
    __syncthreads();
    float tot = red[0] + red[1] + red[2] + red[3];
    float scale = rsqrtf(tot * (1.0f / 512.0f) + 1e-6f);
    float a0 = v0 * scale * W[tid];
    float a1 = v1 * scale * W[tid + 256];
    unsigned short h0 = f2bf(a0), h1 = f2bf(a1);
    size_t base = (size_t)t * 512;
    XNH[base + tid]       = h0;
    XNL[base + tid]       = f2bf(a0 - bf2f(h0));
    XNH[base + tid + 256] = h1;
    XNL[base + tid + 256] = f2bf(a1 - bf2f(h1));
}

// ---- bf16x3 MFMA GEMM, pre-split A and B: C = A @ B^T (+Res / atomic) -----
// 128x128 tile, BK=32, 256 thr = 4 waves, each wave 64x64 = 4x4 mfma tiles.
// Split-K via blockIdx.z: block covers K range [z*Kc, (z+1)*Kc).
template <bool ATOMIC>
__global__ __launch_bounds__(256) void gemm2(
        const ushort_t* __restrict__ AH, const ushort_t* __restrict__ AL,
        const ushort_t* __restrict__ BH, const ushort_t* __restrict__ BL,
        const float* __restrict__ Res, float* __restrict__ C,
        int M, int N, int Kfull, int Kc) {
    __shared__ __align__(16) unsigned short Ah[128][40];  // pad 32->40
    __shared__ __align__(16) unsigned short Al[128][40];
    __shared__ __align__(16) unsigned short Bh[128][40];
    __shared__ __align__(16) unsigned short Bl[128][40];
    int tid = threadIdx.x;
    int n0 = blockIdx.x * 128, m0 = blockIdx.y * 128;
    int koff = blockIdx.z * Kc;
    int wid = tid >> 6, lane = tid & 63;
    int wm = (wid >> 1) * 64, wn = (wid & 1) * 64;
    int col = lane & 15, quad = lane >> 4;
    int sr = tid >> 1, sc = (tid & 1) * 16;
    const ushort_t* AHg = AH + (size_t)(m0 + sr) * Kfull + koff + sc;
    const ushort_t* ALg = AL + (size_t)(m0 + sr) * Kfull + koff + sc;
    const ushort_t* BHg = BH + (size_t)(n0 + sr) * Kfull + koff + sc;
    const ushort_t* BLg = BL + (size_t)(n0 + sr) * Kfull + koff + sc;

    f32x4 acc[4][4] = {};
    uint4 ahr[2], alr[2], bhr[2], blr[2];
    ahr[0] = *(const uint4*)AHg;  ahr[1] = *(const uint4*)(AHg + 8);
    alr[0] = *(const uint4*)ALg;  alr[1] = *(const uint4*)(ALg + 8);
    bhr[0] = *(const uint4*)BHg;  bhr[1] = *(const uint4*)(BHg + 8);
    blr[0] = *(const uint4*)BLg;  blr[1] = *(const uint4*)(BLg + 8);

    int nk = Kc >> 5;
#pragma unroll 1
    for (int kc = 0; kc < nk; ++kc) {
        if (kc) __syncthreads();
        *(uint4*)&Ah[sr][sc]     = ahr[0];
        *(uint4*)&Ah[sr][sc + 8] = ahr[1];
        *(uint4*)&Al[sr][sc]     = alr[0];
        *(uint4*)&Al[sr][sc + 8] = alr[1];
        *(uint4*)&Bh[sr][sc]     = bhr[0];
        *(uint4*)&Bh[sr][sc + 8] = bhr[1];
        *(uint4*)&Bl[sr][sc]     = blr[0];
        *(uint4*)&Bl[sr][sc + 8] = blr[1];
        __syncthreads();
        if (kc + 1 < nk) {   // prefetch next chunk (overlaps MFMA below)
            int k0 = (kc + 1) * 32;
            ahr[0] = *(const uint4*)(AHg + k0);  ahr[1] = *(const uint4*)(AHg + k0 + 8);
            alr[0] = *(const uint4*)(ALg + k0);  alr[1] = *(const uint4*)(ALg + k0 + 8);
            bhr[0] = *(const uint4*)(BHg + k0);  bhr[1] = *(const uint4*)(BHg + k0 + 8);
            blr[0] = *(const uint4*)(BLg + k0);  blr[1] = *(const uint4*)(BLg + k0 + 8);
        }
        short8 afh[4], afl[4], bfh[4], bfl[4];
#pragma unroll
        for (int i = 0; i < 4; ++i) {
            afh[i] = *(const short8*)&Ah[wm + i * 16 + col][quad * 8];
            afl[i] = *(const short8*)&Al[wm + i * 16 + col][quad * 8];
            bfh[i] = *(const short8*)&Bh[wn + i * 16 + col][quad * 8];
            bfl[i] = *(const short8*)&Bl[wn + i * 16 + col][quad * 8];
        }
#pragma unroll
        for (int mi = 0; mi < 4; ++mi)
#pragma unroll
            for (int ni = 0; ni < 4; ++ni) {
                f32x4 c = acc[mi][ni];
                c = MFMA16(afh[mi], bfh[ni], c);
                c = MFMA16(afh[mi], bfl[ni], c);
                c = MFMA16(afl[mi], bfh[ni], c);
                acc[mi][ni] = c;
            }
    }
    // epilogue: C/D layout col=lane&15, row=quad*4+reg
#pragma unroll
    for (int mi = 0; mi < 4; ++mi)
#pragma unroll
        for (int ni = 0; ni < 4; ++ni)
#pragma unroll
            for (int r = 0; r < 4; ++r) {
                int row = m0 + wm + mi * 16 + quad * 4 + r;
                int ccol = n0 + wn + ni * 16 + col;
                size_t o = (size_t)row * N + ccol;
                float v = acc[mi][ni][r];
                if (ATOMIC) {
                    atomicAdd(C + o, v);
                } else {
                    if (Res) v += Res[o];
                    C[o] = v;
                }
            }
}

// ---- split qkv + RoPE + transpose to (g,h,s,hd) ---------------------------
__global__ void rope_pack_kernel(const float* __restrict__ QKV, float* __restrict__ Q,
        float* __restrict__ K, float* __restrict__ V, int Sg, int total) {
    int idx = blockIdx.x * 256 + threadIdx.x;
    if (idx >= total) return;
    int i = idx & 31;
    int h = (idx >> 5) & 7;
    int t = idx >> 8;
    int g = t / Sg; int s = t - g * Sg;
    const float* row = QKV + (size_t)t * 1536;
    float inv = powf(10000.0f, -(float)(2 * i) / 64.0f);
    float sn, cs;
    sincosf((float)s * inv, &sn, &cs);
    size_t ob = ((size_t)(g * 8 + h) * Sg + s) * 64 + i;
    int c = h * 64 + i;
    float q1 = row[c], q2 = row[c + 32];
    Q[ob]      = q1 * cs + q2 * sn;
    Q[ob + 32] = q2 * cs - q1 * sn;
    float k1 = row[512 + c], k2 = row[512 + c + 32];
    K[ob]      = k1 * cs + k2 * sn;
    K[ob + 32] = k2 * cs - k1 * sn;
    V[ob]      = row[1024 + c];
    V[ob + 32] = row[1024 + c + 32];
}

// ---- MFMA flash attention (bf16x3 scores & PV), emits AO as bf16 hi/lo ----
template <bool MASKED>
__global__ __launch_bounds__(256) void attn3_kernel(const float* __restrict__ Q,
        const float* __restrict__ K, const float* __restrict__ V,
        const int* __restrict__ doc, ushort_t* __restrict__ AOH,
        ushort_t* __restrict__ AOL, int Sg) {
    __shared__ __align__(16) unsigned short Kh[64][72], Kl[64][72];
    __shared__ __align__(16) unsigned short Vth[64][72], Vtl[64][72];
    __shared__ __align__(16) unsigned short Ph[4][16][72], Pl[4][16][72];
    __shared__ int dock[64];
    int qb = (int)(gridDim.x - 1 - blockIdx.x);   // big qb first (load balance)
    int gh = blockIdx.y, g = gh >> 3;
    int tid = threadIdx.x, wid = tid >> 6, lane = tid & 63;
    int col = lane & 15, quad = lane >> 4;
    int srr = tid >> 2, scc = (tid & 3) * 16;

    short8 qa[2][2];  // [kk][0=hi,1=lo]
    {
        int qrow = qb * 64 + wid * 16 + col;
        if (qrow >= Sg) qrow = Sg - 1;
        const float* Qg = Q + ((size_t)gh * Sg + qrow) * 64 + quad * 8;
#pragma unroll
        for (int kk = 0; kk < 2; ++kk) {
            float4 v0 = *(const float4*)(Qg + kk * 32);
            float4 v1 = *(const float4*)(Qg + kk * 32 + 4);
            float vv[8] = {v0.x, v0.y, v0.z, v0.w, v1.x, v1.y, v1.z, v1.w};
            short8 h, l;
#pragma unroll
            for (int e = 0; e < 8; ++e) {
                float x = vv[e] * 0.125f;
                unsigned short hb = f2bf(x);
                h[e] = (short)hb;
                l[e] = (short)f2bf(x - bf2f(hb));
            }
            qa[kk][0] = h; qa[kk][1] = l;
        }
    }
    int dqr[4]; int wq0 = 0, wq1 = 0, bq0 = 0, bq1 = 0;
    if (MASKED) {
        const int* db = doc + (size_t)g * Sg + qb * 64;
#pragma unroll
        for (int r = 0; r < 4; ++r) dqr[r] = db[wid * 16 + quad * 4 + r];
        wq0 = db[wid * 16]; wq1 = db[wid * 16 + 15];
        bq0 = db[0];        bq1 = db[63];
    }
    float m[4], l[4];
    f32x4 accO[4];
#pragma unroll
    for (int r = 0; r < 4; ++r) { m[r] = -1e30f; l[r] = 0.f; }
#pragma unroll
    for (int nd = 0; nd < 4; ++nd) accO[nd] = (f32x4){0.f, 0.f, 0.f, 0.f};

    int nkt = MASKED ? (qb + 1) : ((Sg + 63) >> 6);
    for (int kt = 0; kt < nkt; ++kt) {
        int kval = Sg - kt * 64; if (kval > 64) kval = 64;
        __syncthreads();
        if (MASKED && tid < 64) dock[tid] = doc[(size_t)g * Sg + kt * 64 + tid];
        __syncthreads();
        bool bskip = false;
        if (MASKED) bskip = (dock[63] < bq0) || (dock[0] > bq1);
        if (!bskip) {
            {   // stage K (row-major) and V^T, hi/lo split
                int krow = kt * 64 + srr;
                bool okr = krow < Sg;
                const float* Kg = K + ((size_t)gh * Sg + (okr ? krow : 0)) * 64 + scc;
                const float* Vg = V + ((size_t)gh * Sg + (okr ? krow : 0)) * 64 + scc;
#pragma unroll
                for (int t = 0; t < 4; ++t) {
                    float4 kv = okr ? *(const float4*)(Kg + 4 * t) : make_float4(0.f, 0.f, 0.f, 0.f);
                    float4 vv = okr ? *(const float4*)(Vg + 4 * t) : make_float4(0.f, 0.f, 0.f, 0.f);
                    float ka[4] = {kv.x, kv.y, kv.z, kv.w};
                    float va[4] = {vv.x, vv.y, vv.z, vv.w};
#pragma unroll
                    for (int e = 0; e < 4; ++e) {
                        int d = scc + 4 * t + e;
                        unsigned short h = f2bf(ka[e]);
                        Kh[srr][d] = h;
                        Kl[srr][d] = f2bf(ka[e] - bf2f(h));
                        unsigned short vh = f2bf(va[e]);
                        Vth[d][srr] = vh;
                        Vtl[d][srr] = f2bf(va[e] - bf2f(vh));
                    }
                }
            }
            __syncthreads();
            bool wskip = false;
            if (MASKED) wskip = (dock[kval - 1] < wq0) || (dock[0] > wq1);
            if (!wskip) {
                int dk[4];
                if (MASKED) {
#pragma unroll
                    for (int ni = 0; ni < 4; ++ni) dk[ni] = dock[ni * 16 + col];
                }
                f32x4 sc[4];
#pragma unroll
                for (int ni = 0; ni < 4; ++ni) {
                    f32x4 c = (f32x4){0.f, 0.f, 0.f, 0.f};
#pragma unroll
                    for (int kk = 0; kk < 2; ++kk) {
                        short8 bh = *(const short8*)&Kh[ni * 16 + col][kk * 32 + quad * 8];
                        short8 bl = *(const short8*)&Kl[ni * 16 + col][kk * 32 + quad * 8];
                        c = MFMA16(qa[kk][0], bh, c);
                        c = MFMA16(qa[kk][0], bl, c);
                        c = MFMA16(qa[kk][1], bh, c);
                    }
                    sc[ni] = c;
                }
                float mnew[4];
#pragma unroll
                for (int r = 0; r < 4; ++r) mnew[r] = -1e30f;
#pragma unroll
                for (int ni = 0; ni < 4; ++ni)
#pragma unroll
                    for (int r = 0; r < 4; ++r) {
                        bool ok = MASKED ? (dk[ni] == dqr[r]) : (ni * 16 + col < kval);
                        float s = ok ? sc[ni][r] : -1e30f;
                        sc[ni][r] = s;
                        mnew[r] = fmaxf(mnew[r], s);
                    }
#pragma unroll
                for (int r = 0; r < 4; ++r)
#pragma unroll
                    for (int o = 1; o < 16; o <<= 1)
                        mnew[r] = fmaxf(mnew[r], __shfl_xor(mnew[r], o));
                float alpha[4], lsum[4];
#pragma unroll
                for (int r = 0; r < 4; ++r) {
                    float M = fmaxf(m[r], mnew[r]);
                    alpha[r] = __expf(m[r] - M);
                    m[r] = M;
                    lsum[r] = 0.f;
                }
#pragma unroll
                for (int ni = 0; ni < 4; ++ni)
#pragma unroll
                    for (int r = 0; r < 4; ++r) {
                        bool ok = MASKED ? (dk[ni] == dqr[r]) : (ni * 16 + col < kval);
                        float p = ok ? __expf(sc[ni][r] - m[r]) : 0.f;
                        lsum[r] += p;
                        unsigned short h = f2bf(p);
                        Ph[wid][quad * 4 + r][ni * 16 + col] = h;
                        Pl[wid][quad * 4 + r][ni * 16 + col] = f2bf(p - bf2f(h));
                    }
#pragma unroll
                for (int r = 0; r < 4; ++r) {
#pragma unroll
                    for (int o = 1; o < 16; o <<= 1)
                        lsum[r] += __shfl_xor(lsum[r], o);
                    l[r] = l[r] * alpha[r] + lsum[r];
                }
#pragma unroll
                for (int nd = 0; nd < 4; ++nd)
#pragma unroll
                    for (int r = 0; r < 4; ++r) accO[nd][r] *= alpha[r];
#pragma unroll
                for (int kk = 0; kk < 2; ++kk) {
                    short8 pah = *(const short8*)&Ph[wid][col][kk * 32 + quad * 8];
                    short8 pal = *(const short8*)&Pl[wid][col][kk * 32 + quad * 8];
#pragma unroll
                    for (int nd = 0; nd < 4; ++nd) {
                        short8 vbh = *(const short8*)&Vth[nd * 16 + col][kk * 32 + quad * 8];
                        short8 vbl = *(const short8*)&Vtl[nd * 16 + col][kk * 32 + quad * 8];
                        f32x4 c = accO[nd];
                        c = MFMA16(pah, vbh, c);
                        c = MFMA16(pah, vbl, c);
                        c = MFMA16(pal, vbh, c);
                        accO[nd] = c;
                    }
                }
            }
        }
    }
#pragma unroll
    for (int r = 0; r < 4; ++r) {
        int qrow = qb * 64 + wid * 16 + quad * 4 + r;
        if (qrow < Sg) {
            float inv = 1.0f / l[r];
            size_t base = ((size_t)g * Sg + qrow) * 512 + (gh & 7) * 64;
#pragma unroll
            for (int nd = 0; nd < 4; ++nd) {
                float val = accO[nd][r] * inv;
                unsigned short h = f2bf(val);
                AOH[base + nd * 16 + col] = h;
                AOL[base + nd * 16 + col] = f2bf(val - bf2f(h));
            }
        }
    }
}

// ---- silu(h1)*h2, emits bf16 hi/lo ----------------------------------------
__global__ void silu_mul_kernel(const float* __restrict__ H,
        ushort_t* __restrict__ MIDH, ushort_t* __restrict__ MIDL, int total) {
    int idx = blockIdx.x * 256 + threadIdx.x;
    if (idx >= total) return;
    int t = idx >> 10, j = idx & 1023;
    float a = H[(size_t)t * 2048 + j];
    float b = H[(size_t)t * 2048 + 1024 + j];
    float r = (a / (1.0f + __expf(-a))) * b;
    unsigned short h = f2bf(r);
    MIDH[idx] = h;
    MIDL[idx] = f2bf(r - bf2f(h));
}

// ---- build router stream: (64 groups) x (64 tokens + 8 router tokens) -----
__global__ void router_build_kernel(const float* __restrict__ X,
        const float* __restrict__ RT, float* __restrict__ X2, int total) {
    int idx = blockIdx.x * 256 + threadIdx.x;
    if (idx >= total) return;
    int d = idx & 511;
    int p = (idx >> 9) % 72;
    int g2 = idx / (72 * 512);
    X2[idx] = (p < 64) ? X[((size_t)g2 * 64 + p) * 512 + d]
                       : RT[(p - 64) * 512 + d];
}

// ---- gather xr[:,64:72,:] into dense (512,512) bf16 hi/lo -----------------
__global__ void gather_rows_kernel(const float* __restrict__ X2,
        ushort_t* __restrict__ RRH, ushort_t* __restrict__ RRL, int total) {
    int idx = blockIdx.x * 256 + threadIdx.x;
    if (idx >= total) return;
    int d = idx & 511;
    int row = idx >> 9;
    int g2 = row >> 3, rr = row & 7;
    float v = X2[((size_t)(g2 * 72 + 64 + rr)) * 512 + d];
    unsigned short h = f2bf(v);
    RRH[idx] = h;
    RRL[idx] = f2bf(v - bf2f(h));
}

// ---- l2-normalize each 128-half of each out row (l2n commutes w/ expand) --
__global__ __launch_bounds__(64) void norm_half_kernel(const float* __restrict__ IN,
        float* __restrict__ OUT) {
    int b = blockIdx.x; int lane = threadIdx.x;
    size_t base = (size_t)(b >> 1) * 256 + (size_t)(b & 1) * 128;
    float v0 = IN[base + lane], v1 = IN[base + 64 + lane];
    float ss = wave_sum64(v0 * v0 + v1 * v1);
    float sc = 1.0f / fmaxf(sqrtf(ss), 1e-12f);
    OUT[base + lane]      = v0 * sc;
    OUT[base + 64 + lane] = v1 * sc;
}

// ---- l2-normalize key columns: keys (32,128,16) over d --------------------
__global__ __launch_bounds__(64) void norm_keys_kernel(const float* __restrict__ Kin,
        float* __restrict__ Kout) {
    int b = blockIdx.x; int lane = threadIdx.x;
    int g = b >> 4, e = b & 15;
    size_t base = (size_t)g * 2048 + e;
    float v0 = Kin[base + (size_t)lane * 16];
    float v1 = Kin[base + (size_t)(lane + 64) * 16];
    float ss = wave_sum64(v0 * v0 + v1 * v1);
    float sc = 1.0f / fmaxf(sqrtf(ss), 1e-12f);
    Kout[base + (size_t)lane * 16]        = v0 * sc;
    Kout[base + (size_t)(lane + 64) * 16] = v1 * sc;
}

// ---- logits + top2 (stable, jax tie-break) --------------------------------
__global__ __launch_bounds__(64) void logits_top2_kernel(const float* __restrict__ OUTN,
        const float* __restrict__ KRN, const float* __restrict__ KGN,
        float* __restrict__ out) {
    int blk = blockIdx.x;
    int g = blk >> 6, bcol = blk & 63;
    int b = bcol >> 5, l = bcol & 31;
    int lsrc = (l + 31) & 31;     // roll(+1): element l comes from l-1
    int r = g >> 2;               // repeat RM=4
    int row = (b * 32 + lsrc) * 8 + r;
    const float* rvec = OUTN + (size_t)row * 256;
    __shared__ float sc[32];
    int lane = threadIdx.x;
    if (lane < 32) {
        int e = lane & 15;
        const float* kb = ((lane < 16) ? KRN : KGN) + (size_t)g * 2048 + e;
        const float* xv = (lane < 16) ? rvec : (rvec + 128);
        float s = 0.f;
#pragma unroll 8
        for (int d = 0; d < 128; ++d) s = fmaf(xv[d], kb[(size_t)d * 16], s);
        sc[lane] = s;
    }
    __syncthreads();
    if (lane == 0) {
        float bv = -1e30f, sv = -1e30f; int bi = 0, si = 0;
#pragma unroll
        for (int e = 0; e < 16; ++e) {
            float v = sc[e];
            if (v > bv) { sv = bv; si = bi; bv = v; bi = e; }
            else if (v > sv) { sv = v; si = e; }
        }
        size_t base = (size_t)g * 128 + (size_t)bcol * 2;
        out[base]            = bv;
        out[base + 1]        = sv;
        out[4096 + base]     = sc[16 + bi];
        out[4096 + base + 1] = sc[16 + si];
    }
}

// ---------------------------------------------------------------------------
static void run_layer(float* X, float* BIG, float* Qb, float* Kb, float* Vb,
                      ushort_t* XNH, ushort_t* XNL, ushort_t* AOH, ushort_t* AOL,
                      ushort_t* MIDH, ushort_t* MIDL,
                      const unsigned short* WH, const unsigned short* WL,
                      const float* n1, const float* n2,
                      const int* doc, int G, int Sg, hipStream_t stream) {
    const size_t oQKV = 0, oO = 786432, oUP = 1048576, oDN = 2097152;
    int T = G * Sg;
    rmsnorm_kernel<<<T, 256, 0, stream>>>(X, n1, XNH, XNL);
    gemm2<false><<<dim3(12, T / 128), 256, 0, stream>>>(XNH, XNL, WH + oQKV, WL + oQKV, nullptr, BIG, T, 1536, 512, 512);
    int rp = T * 256;
    rope_pack_kernel<<<(rp + 255) / 256, 256, 0, stream>>>(BIG, Qb, Kb, Vb, Sg, rp);
    int qblocks = (Sg + 63) >> 6;
    if (doc)
        attn3_kernel<true><<<dim3(qblocks, G * 8), 256, 0, stream>>>(Qb, Kb, Vb, doc, AOH, AOL, Sg);
    else
        attn3_kernel<false><<<dim3(qblocks, G * 8), 256, 0, stream>>>(Qb, Kb, Vb, nullptr, AOH, AOL, Sg);
    // o-proj: split-K=4, atomicAdd into X (X already holds the residual)
    gemm2<true><<<dim3(4, T / 128, 4), 256, 0, stream>>>(AOH, AOL, WH + oO, WL + oO, nullptr, X, T, 512, 512, 128);
    rmsnorm_kernel<<<T, 256, 0, stream>>>(X, n2, XNH, XNL);
    gemm2<false><<<dim3(16, T / 128), 256, 0, stream>>>(XNH, XNL, WH + oUP, WL + oUP, nullptr, BIG, T, 2048, 512, 512);
    silu_mul_kernel<<<(T * 1024 + 255) / 256, 256, 0, stream>>>(BIG, MIDH, MIDL, T * 1024);
    // down-proj: split-K=4, atomicAdd into X
    gemm2<true><<<dim3(4, T / 128, 4), 256, 0, stream>>>(MIDH, MIDL, WH + oDN, WL + oDN, nullptr, X, T, 512, 1024, 256);
}

static void split_layer(const float* qkv, const float* o, const float* up, const float* dn,
                        unsigned short* WH, unsigned short* WL, hipStream_t stream) {
    const size_t oQKV = 0, oO = 786432, oUP = 1048576, oDN = 2097152;
    wsplit_kernel<<<dim3(48, 16), 256, 0, stream>>>(qkv, WH + oQKV, WL + oQKV, 512, 1536);
    wsplit_kernel<<<dim3(16, 16), 256, 0, stream>>>(o,   WH + oO,   WL + oO,   512, 512);
    wsplit_kernel<<<dim3(64, 16), 256, 0, stream>>>(up,  WH + oUP,  WL + oUP,  512, 2048);
    wsplit_kernel<<<dim3(16, 32), 256, 0, stream>>>(dn,  WH + oDN,  WL + oDN,  1024, 512);
}

extern "C" void kernel_launch(void* const* d_in, const int* in_sizes, int n_in,
                              void* d_out, int out_size, void* d_ws, size_t ws_size,
                              hipStream_t stream) {
    const float* x_in    = (const float*)d_in[0];
    const int*   doc     = (const int*)d_in[1];
    const float* rt      = (const float*)d_in[2];
    const float* out_w   = (const float*)d_in[3];
    const float* k_rt    = (const float*)d_in[4];
    const float* k_gt    = (const float*)d_in[5];
    const float* enc_qkv = (const float*)d_in[6];
    const float* enc_o   = (const float*)d_in[7];
    const float* enc_up  = (const float*)d_in[8];
    const float* enc_dn  = (const float*)d_in[9];
    const float* enc_n1  = (const float*)d_in[10];
    const float* enc_n2  = (const float*)d_in[11];
    const float* rtr_qkv = (const float*)d_in[12];
    const float* rtr_o   = (const float*)d_in[13];
    const float* rtr_up  = (const float*)d_in[14];
    const float* rtr_dn  = (const float*)d_in[15];
    const float* rtr_n1  = (const float*)d_in[16];
    const float* rtr_n2  = (const float*)d_in[17];

    float* ws = (float*)d_ws;
    size_t off = 0;
    auto alloc = [&](size_t n) { float* p = ws + off; off += n; return p; };
    float* X    = alloc(4608UL * 512);
    float* X2   = alloc(4608UL * 512);
    float* BIG  = alloc(4608UL * 2048);
    float* Qb   = alloc(4608UL * 512);
    float* Kb   = alloc(4608UL * 512);
    float* Vb   = alloc(4608UL * 512);
    unsigned short* WH = (unsigned short*)(ws + off);
    unsigned short* WL = WH + 2621440UL;
    off += 2621440UL;
    // ---- dead-range aliases (stream-ordered, non-overlapping lifetimes) ----
    // XN hi/lo (T x 512 ushort each = 9.44MB total) -> Qb (9.44MB).
    //   XN live rms->gemm; Qb (rope Q) live rope->attn. Disjoint.
    ushort_t* XNH = (ushort_t*)Qb;
    ushort_t* XNL = XNH + 4608UL * 512;
    // MID hi/lo (T x 1024 ushort each = 9.44MB each) -> Qb and Kb exactly.
    ushort_t* MIDH = (ushort_t*)Qb;
    ushort_t* MIDL = (ushort_t*)Kb;
    // AO hi/lo (T x 512 each) -> BIG (dead between rope and up-gemm).
    ushort_t* AOH = (ushort_t*)BIG;
    ushort_t* AOL = AOH + 4608UL * 512;
    // X dead after router_build -> tail buffers:
    ushort_t* RRH = (ushort_t*)X;              // 512x512 ushort
    ushort_t* RRL = RRH + 262144;              // (both within X[0:131072+131072))
    float* OUTM = X + 262144;
    float* OUTN = X + 393216;
    float* KRN  = X + 524288;
    float* KGN  = X + 589824;
    (void)ws_size; (void)in_sizes; (void)n_in; (void)out_size;

    copy_in_kernel<<<(2097152 + 255) / 256, 256, 0, stream>>>(x_in, X, 2097152);

    for (int i = 0; i < 4; ++i) {
        split_layer(enc_qkv + (size_t)i * 512 * 1536,
                    enc_o   + (size_t)i * 512 * 512,
                    enc_up  + (size_t)i * 512 * 2048,
                    enc_dn  + (size_t)i * 1024 * 512, WH, WL, stream);
        run_layer(X, BIG, Qb, Kb, Vb, XNH, XNL, AOH, AOL, MIDH, MIDL, WH, WL,
                  enc_n1 + (size_t)i * 512, enc_n2 + (size_t)i * 512,
                  doc, 2, 2048, stream);
    }

    int rb_total = 64 * 72 * 512;
    router_build_kernel<<<(rb_total + 255) / 256, 256, 0, stream>>>(X, rt, X2, rb_total);

    for (int i = 0; i < 2; ++i) {
        split_layer(rtr_qkv + (size_t)i * 512 * 1536,
                    rtr_o   + (size_t)i * 512 * 512,
                    rtr_up  + (size_t)i * 512 * 2048,
                    rtr_dn  + (size_t)i * 1024 * 512, WH, WL, stream);
        run_layer(X2, BIG, Qb, Kb, Vb, XNH, XNL, AOH, AOL, MIDH, MIDL, WH, WL,
                  rtr_n1 + (size_t)i * 512, rtr_n2 + (size_t)i * 512,
                  nullptr, 64, 72, stream);
    }

    gather_rows_kernel<<<(512 * 512) / 256, 256, 0, stream>>>(X2, RRH, RRL, 512 * 512);
    wsplit_kernel<<<dim3(8, 16), 256, 0, stream>>>(out_w, WH, WL, 512, 256);
    gemm2<false><<<dim3(2, 4), 256, 0, stream>>>(RRH, RRL, WH, WL, nullptr, OUTM, 512, 256, 512, 512);

    norm_half_kernel<<<1024, 64, 0, stream>>>(OUTM, OUTN);
    norm_keys_kernel<<<512, 64, 0, stream>>>(k_rt, KRN);
    norm_keys_kernel<<<512, 64, 0, stream>>>(k_gt, KGN);
    logits_top2_kernel<<<2048, 64, 0, stream>>>(OUTN, KRN, KGN, (float*)d_out);
}

// Round 9
// 1582.266 us; speedup vs baseline: 1.6018x; 1.6018x over previous
//
#include <hip/hip_runtime.h>
#include <hip/hip_bf16.h>
#include <cstdint>

// ---------------------------------------------------------------------------
// B=2 S=2048 D=512 H=8 HD=64, FFH=1024. Encoder: 4 layers, G=2, Sg=2048
// (block-causal-64 AND doc mask). Router: 2 layers, G=64, Sg=72, full attn.
// Round 9: revert round-8 atomics (regression: 218MB atomic writes, 30ms
// dispatch). GEMM staging -> __builtin_amdgcn_global_load_lds width=16,
// unpadded LDS rows (uniform bank access). Pre-split-A producers kept.
// ---------------------------------------------------------------------------

typedef __attribute__((ext_vector_type(8))) short short8;   // 8 bf16 = 4 VGPR
typedef __attribute__((ext_vector_type(4))) float f32x4;
typedef unsigned short ushort_t;

__device__ __forceinline__ float bf2f(unsigned short u) {
    return __uint_as_float(((unsigned)u) << 16);
}
__device__ __forceinline__ unsigned short f2bf(float f) {
    unsigned u = __float_as_uint(f);
    unsigned r = 0x7FFFu + ((u >> 16) & 1u);
    return (unsigned short)((u + r) >> 16);
}
__device__ __forceinline__ float wave_sum64(float v) {
#pragma unroll
    for (int o = 32; o; o >>= 1) v += __shfl_xor(v, o);
    return v;
}
__device__ __forceinline__ void load_lds16(const ushort_t* g, ushort_t* l) {
    __builtin_amdgcn_global_load_lds(
        (const __attribute__((address_space(1))) unsigned int*)g,
        (__attribute__((address_space(3))) unsigned int*)l, 16, 0, 0);
}

#define MFMA16(a, b, c) __builtin_amdgcn_mfma_f32_16x16x32_bf16(a, b, c, 0, 0, 0)

// ---- f32 copy (input x -> mutable X) --------------------------------------
__global__ void copy_in_kernel(const float* __restrict__ src,
                               float* __restrict__ dst, int n) {
    int i = blockIdx.x * 256 + threadIdx.x;
    if (i < n) dst[i] = src[i];
}

// ---- weight transpose + hi/lo bf16 split: W[K,N] -> WT_hi/lo[N,K] ---------
__global__ __launch_bounds__(256) void wsplit_kernel(const float* __restrict__ W,
        unsigned short* __restrict__ WH, unsigned short* __restrict__ WL,
        int K, int N) {
    __shared__ float tile[32][33];
    int bn = blockIdx.x * 32, bk = blockIdx.y * 32;
    int tx = threadIdx.x & 31, ty = threadIdx.x >> 5;
#pragma unroll
    for (int i = 0; i < 4; ++i)
        tile[ty + 8 * i][tx] = W[(size_t)(bk + ty + 8 * i) * N + bn + tx];
    __syncthreads();
#pragma unroll
    for (int i = 0; i < 4; ++i) {
        int n = bn + ty + 8 * i, k = bk + tx;
        float x = tile[tx][ty + 8 * i];
        unsigned short h = f2bf(x);
        unsigned short lo = f2bf(x - bf2f(h));
        WH[(size_t)n * K + k] = h;
        WL[(size_t)n * K + k] = lo;
    }
}

// ---- RMSNorm over D=512, emits bf16 hi/lo ---------------------------------
__global__ __launch_bounds__(256) void rmsnorm_kernel(const float* __restrict__ X,
        const float* __restrict__ W, ushort_t* __restrict__ XNH,
        ushort_t* __restrict__ XNL) {
    int t = blockIdx.x, tid = threadIdx.x;
    const float* xr = X + (size_t)t * 512;
    float v0 = xr[tid], v1 = xr[tid + 256];
    float ss = wave_sum64(v0 * v0 + v1 * v1);
    __shared__ float red[4];
    if ((tid & 63) == 0) red[tid >> 6] = ss;
    __syncthreads();
    float tot = red[0] + red[1] + red[2] + red[3];
    float scale = rsqrtf(tot * (1.0f / 512.0f) + 1e-6f);
    float a0 = v0 * scale * W[tid];
    float a1 = v1 * scale * W[tid + 256];
    unsigned short h0 = f2bf(a0), h1 = f2bf(a1);
    size_t base = (size_t)t * 512;
    XNH[base + tid]       = h0;
    XNL[base + tid]       = f2bf(a0 - bf2f(h0));
    XNH[base + tid + 256] = h1;
    XNL[base + tid + 256] = f2bf(a1 - bf2f(h1));
}

// ---- bf16x3 MFMA GEMM, pre-split A/B, global_load_lds staging -------------
// C[M,N] = A @ B^T (+Res). 128x128 tile, BK=32, 256 thr = 4 waves, each wave
// 64x64 = 4x4 mfma frags. Wave wid stages one of {Ah,Al,Bh,Bl} (8KB) via
// 8x global_load_lds(16B): lane L -> LDS base+16L == row L>>2, chunk L&3.
__global__ __launch_bounds__(256) void gemm3(
        const ushort_t* __restrict__ AH, const ushort_t* __restrict__ AL,
        const ushort_t* __restrict__ BH, const ushort_t* __restrict__ BL,
        const float* __restrict__ Res, float* __restrict__ C,
        int M, int N, int K) {
    __shared__ __align__(16) ushort_t Ah[128][32];   // unpadded: uniform banks
    __shared__ __align__(16) ushort_t Al[128][32];
    __shared__ __align__(16) ushort_t Bh[128][32];
    __shared__ __align__(16) ushort_t Bl[128][32];
    int tid = threadIdx.x;
    int n0 = blockIdx.x * 128, m0 = blockIdx.y * 128;
    int wid = tid >> 6, lane = tid & 63;
    int wm = (wid >> 1) * 64, wn = (wid & 1) * 64;
    int col = lane & 15, quad = lane >> 4;

    // this wave's staging assignment
    const ushort_t* gb;
    ushort_t* lb;
    if (wid == 0)      { gb = AH + (size_t)m0 * K; lb = &Ah[0][0]; }
    else if (wid == 1) { gb = AL + (size_t)m0 * K; lb = &Al[0][0]; }
    else if (wid == 2) { gb = BH + (size_t)n0 * K; lb = &Bh[0][0]; }
    else               { gb = BL + (size_t)n0 * K; lb = &Bl[0][0]; }
    const ushort_t* gsrc = gb + (size_t)(lane >> 2) * K + (lane & 3) * 8;

    f32x4 acc[4][4] = {};
    int nk = K >> 5;
#pragma unroll 1
    for (int kc = 0; kc < nk; ++kc) {
        int k0 = kc * 32;
        if (kc) __syncthreads();           // prior frag reads complete
#pragma unroll
        for (int p = 0; p < 8; ++p)
            load_lds16(gsrc + (size_t)(p * 16) * K + k0, lb + p * 512);
        __syncthreads();                   // barrier drains vmcnt
        short8 afh[4], afl[4], bfh[4], bfl[4];
#pragma unroll
        for (int i = 0; i < 4; ++i) {
            afh[i] = *(const short8*)&Ah[wm + i * 16 + col][quad * 8];
            afl[i] = *(const short8*)&Al[wm + i * 16 + col][quad * 8];
            bfh[i] = *(const short8*)&Bh[wn + i * 16 + col][quad * 8];
            bfl[i] = *(const short8*)&Bl[wn + i * 16 + col][quad * 8];
        }
#pragma unroll
        for (int mi = 0; mi < 4; ++mi)
#pragma unroll
            for (int ni = 0; ni < 4; ++ni) {
                f32x4 c = acc[mi][ni];
                c = MFMA16(afh[mi], bfh[ni], c);
                c = MFMA16(afh[mi], bfl[ni], c);
                c = MFMA16(afl[mi], bfh[ni], c);
                acc[mi][ni] = c;
            }
    }
    // epilogue: C/D layout col=lane&15, row=quad*4+reg
#pragma unroll
    for (int mi = 0; mi < 4; ++mi)
#pragma unroll
        for (int ni = 0; ni < 4; ++ni)
#pragma unroll
            for (int r = 0; r < 4; ++r) {
                int row = m0 + wm + mi * 16 + quad * 4 + r;
                int ccol = n0 + wn + ni * 16 + col;
                size_t o = (size_t)row * N + ccol;
                float v = acc[mi][ni][r];
                if (Res) v += Res[o];
                C[o] = v;
            }
}

// ---- split qkv + RoPE + transpose to (g,h,s,hd) ---------------------------
__global__ void rope_pack_kernel(const float* __restrict__ QKV, float* __restrict__ Q,
        float* __restrict__ K, float* __restrict__ V, int Sg, int total) {
    int idx = blockIdx.x * 256 + threadIdx.x;
    if (idx >= total) return;
    int i = idx & 31;
    int h = (idx >> 5) & 7;
    int t = idx >> 8;
    int g = t / Sg; int s = t - g * Sg;
    const float* row = QKV + (size_t)t * 1536;
    float inv = powf(10000.0f, -(float)(2 * i) / 64.0f);
    float sn, cs;
    sincosf((float)s * inv, &sn, &cs);
    size_t ob = ((size_t)(g * 8 + h) * Sg + s) * 64 + i;
    int c = h * 64 + i;
    float q1 = row[c], q2 = row[c + 32];
    Q[ob]      = q1 * cs + q2 * sn;
    Q[ob + 32] = q2 * cs - q1 * sn;
    float k1 = row[512 + c], k2 = row[512 + c + 32];
    K[ob]      = k1 * cs + k2 * sn;
    K[ob + 32] = k2 * cs - k1 * sn;
    V[ob]      = row[1024 + c];
    V[ob + 32] = row[1024 + c + 32];
}

// ---- MFMA flash attention (bf16x3 scores & PV), emits AO as bf16 hi/lo ----
template <bool MASKED>
__global__ __launch_bounds__(256) void attn3_kernel(const float* __restrict__ Q,
        const float* __restrict__ K, const float* __restrict__ V,
        const int* __restrict__ doc, ushort_t* __restrict__ AOH,
        ushort_t* __restrict__ AOL, int Sg) {
    __shared__ __align__(16) unsigned short Kh[64][72], Kl[64][72];
    __shared__ __align__(16) unsigned short Vth[64][72], Vtl[64][72];
    __shared__ __align__(16) unsigned short Ph[4][16][72], Pl[4][16][72];
    __shared__ int dock[64];
    int qb = (int)(gridDim.x - 1 - blockIdx.x);   // big qb first (load balance)
    int gh = blockIdx.y, g = gh >> 3;
    int tid = threadIdx.x, wid = tid >> 6, lane = tid & 63;
    int col = lane & 15, quad = lane >> 4;
    int srr = tid >> 2, scc = (tid & 3) * 16;

    short8 qa[2][2];  // [kk][0=hi,1=lo]
    {
        int qrow = qb * 64 + wid * 16 + col;
        if (qrow >= Sg) qrow = Sg - 1;
        const float* Qg = Q + ((size_t)gh * Sg + qrow) * 64 + quad * 8;
#pragma unroll
        for (int kk = 0; kk < 2; ++kk) {
            float4 v0 = *(const float4*)(Qg + kk * 32);
            float4 v1 = *(const float4*)(Qg + kk * 32 + 4);
            float vv[8] = {v0.x, v0.y, v0.z, v0.w, v1.x, v1.y, v1.z, v1.w};
            short8 h, l;
#pragma unroll
            for (int e = 0; e < 8; ++e) {
                float x = vv[e] * 0.125f;
                unsigned short hb = f2bf(x);
                h[e] = (short)hb;
                l[e] = (short)f2bf(x - bf2f(hb));
            }
            qa[kk][0] = h; qa[kk][1] = l;
        }
    }
    int dqr[4]; int wq0 = 0, wq1 = 0, bq0 = 0, bq1 = 0;
    if (MASKED) {
        const int* db = doc + (size_t)g * Sg + qb * 64;
#pragma unroll
        for (int r = 0; r < 4; ++r) dqr[r] = db[wid * 16 + quad * 4 + r];
        wq0 = db[wid * 16]; wq1 = db[wid * 16 + 15];
        bq0 = db[0];        bq1 = db[63];
    }
    float m[4], l[4];
    f32x4 accO[4];
#pragma unroll
    for (int r = 0; r < 4; ++r) { m[r] = -1e30f; l[r] = 0.f; }
#pragma unroll
    for (int nd = 0; nd < 4; ++nd) accO[nd] = (f32x4){0.f, 0.f, 0.f, 0.f};

    int nkt = MASKED ? (qb + 1) : ((Sg + 63) >> 6);
    for (int kt = 0; kt < nkt; ++kt) {
        int kval = Sg - kt * 64; if (kval > 64) kval = 64;
        __syncthreads();
        if (MASKED && tid < 64) dock[tid] = doc[(size_t)g * Sg + kt * 64 + tid];
        __syncthreads();
        bool bskip = false;
        if (MASKED) bskip = (dock[63] < bq0) || (dock[0] > bq1);
        if (!bskip) {
            {   // stage K (row-major) and V^T, hi/lo split
                int krow = kt * 64 + srr;
                bool okr = krow < Sg;
                const float* Kg = K + ((size_t)gh * Sg + (okr ? krow : 0)) * 64 + scc;
                const float* Vg = V + ((size_t)gh * Sg + (okr ? krow : 0)) * 64 + scc;
#pragma unroll
                for (int t = 0; t < 4; ++t) {
                    float4 kv = okr ? *(const float4*)(Kg + 4 * t) : make_float4(0.f, 0.f, 0.f, 0.f);
                    float4 vv = okr ? *(const float4*)(Vg + 4 * t) : make_float4(0.f, 0.f, 0.f, 0.f);
                    float ka[4] = {kv.x, kv.y, kv.z, kv.w};
                    float va[4] = {vv.x, vv.y, vv.z, vv.w};
#pragma unroll
                    for (int e = 0; e < 4; ++e) {
                        int d = scc + 4 * t + e;
                        unsigned short h = f2bf(ka[e]);
                        Kh[srr][d] = h;
                        Kl[srr][d] = f2bf(ka[e] - bf2f(h));
                        unsigned short vh = f2bf(va[e]);
                        Vth[d][srr] = vh;
                        Vtl[d][srr] = f2bf(va[e] - bf2f(vh));
                    }
                }
            }
            __syncthreads();
            bool wskip = false;
            if (MASKED) wskip = (dock[kval - 1] < wq0) || (dock[0] > wq1);
            if (!wskip) {
                int dk[4];
                if (MASKED) {
#pragma unroll
                    for (int ni = 0; ni < 4; ++ni) dk[ni] = dock[ni * 16 + col];
                }
                f32x4 sc[4];
#pragma unroll
                for (int ni = 0; ni < 4; ++ni) {
                    f32x4 c = (f32x4){0.f, 0.f, 0.f, 0.f};
#pragma unroll
                    for (int kk = 0; kk < 2; ++kk) {
                        short8 bh = *(const short8*)&Kh[ni * 16 + col][kk * 32 + quad * 8];
                        short8 bl = *(const short8*)&Kl[ni * 16 + col][kk * 32 + quad * 8];
                        c = MFMA16(qa[kk][0], bh, c);
                        c = MFMA16(qa[kk][0], bl, c);
                        c = MFMA16(qa[kk][1], bh, c);
                    }
                    sc[ni] = c;
                }
                float mnew[4];
#pragma unroll
                for (int r = 0; r < 4; ++r) mnew[r] = -1e30f;
#pragma unroll
                for (int ni = 0; ni < 4; ++ni)
#pragma unroll
                    for (int r = 0; r < 4; ++r) {
                        bool ok = MASKED ? (dk[ni] == dqr[r]) : (ni * 16 + col < kval);
                        float s = ok ? sc[ni][r] : -1e30f;
                        sc[ni][r] = s;
                        mnew[r] = fmaxf(mnew[r], s);
                    }
#pragma unroll
                for (int r = 0; r < 4; ++r)
#pragma unroll
                    for (int o = 1; o < 16; o <<= 1)
                        mnew[r] = fmaxf(mnew[r], __shfl_xor(mnew[r], o));
                float alpha[4], lsum[4];
#pragma unroll
                for (int r = 0; r < 4; ++r) {
                    float M = fmaxf(m[r], mnew[r]);
                    alpha[r] = __expf(m[r] - M);
                    m[r] = M;
                    lsum[r] = 0.f;
                }
#pragma unroll
                for (int ni = 0; ni < 4; ++ni)
#pragma unroll
                    for (int r = 0; r < 4; ++r) {
                        bool ok = MASKED ? (dk[ni] == dqr[r]) : (ni * 16 + col < kval);
                        float p = ok ? __expf(sc[ni][r] - m[r]) : 0.f;
                        lsum[r] += p;
                        unsigned short h = f2bf(p);
                        Ph[wid][quad * 4 + r][ni * 16 + col] = h;
                        Pl[wid][quad * 4 + r][ni * 16 + col] = f2bf(p - bf2f(h));
                    }
#pragma unroll
                for (int r = 0; r < 4; ++r) {
#pragma unroll
                    for (int o = 1; o < 16; o <<= 1)
                        lsum[r] += __shfl_xor(lsum[r], o);
                    l[r] = l[r] * alpha[r] + lsum[r];
                }
#pragma unroll
                for (int nd = 0; nd < 4; ++nd)
#pragma unroll
                    for (int r = 0; r < 4; ++r) accO[nd][r] *= alpha[r];
#pragma unroll
                for (int kk = 0; kk < 2; ++kk) {
                    short8 pah = *(const short8*)&Ph[wid][col][kk * 32 + quad * 8];
                    short8 pal = *(const short8*)&Pl[wid][col][kk * 32 + quad * 8];
#pragma unroll
                    for (int nd = 0; nd < 4; ++nd) {
                        short8 vbh = *(const short8*)&Vth[nd * 16 + col][kk * 32 + quad * 8];
                        short8 vbl = *(const short8*)&Vtl[nd * 16 + col][kk * 32 + quad * 8];
                        f32x4 c = accO[nd];
                        c = MFMA16(pah, vbh, c);
                        c = MFMA16(pah, vbl, c);
                        c = MFMA16(pal, vbh, c);
                        accO[nd] = c;
                    }
                }
            }
        }
    }
#pragma unroll
    for (int r = 0; r < 4; ++r) {
        int qrow = qb * 64 + wid * 16 + quad * 4 + r;
        if (qrow < Sg) {
            float inv = 1.0f / l[r];
            size_t base = ((size_t)g * Sg + qrow) * 512 + (gh & 7) * 64;
#pragma unroll
            for (int nd = 0; nd < 4; ++nd) {
                float val = accO[nd][r] * inv;
                unsigned short h = f2bf(val);
                AOH[base + nd * 16 + col] = h;
                AOL[base + nd * 16 + col] = f2bf(val - bf2f(h));
            }
        }
    }
}

// ---- silu(h1)*h2, emits bf16 hi/lo ----------------------------------------
__global__ void silu_mul_kernel(const float* __restrict__ H,
        ushort_t* __restrict__ MIDH, ushort_t* __restrict__ MIDL, int total) {
    int idx = blockIdx.x * 256 + threadIdx.x;
    if (idx >= total) return;
    int t = idx >> 10, j = idx & 1023;
    float a = H[(size_t)t * 2048 + j];
    float b = H[(size_t)t * 2048 + 1024 + j];
    float r = (a / (1.0f + __expf(-a))) * b;
    unsigned short h = f2bf(r);
    MIDH[idx] = h;
    MIDL[idx] = f2bf(r - bf2f(h));
}

// ---- build router stream: (64 groups) x (64 tokens + 8 router tokens) -----
__global__ void router_build_kernel(const float* __restrict__ X,
        const float* __restrict__ RT, float* __restrict__ X2, int total) {
    int idx = blockIdx.x * 256 + threadIdx.x;
    if (idx >= total) return;
    int d = idx & 511;
    int p = (idx >> 9) % 72;
    int g2 = idx / (72 * 512);
    X2[idx] = (p < 64) ? X[((size_t)g2 * 64 + p) * 512 + d]
                       : RT[(p - 64) * 512 + d];
}

// ---- gather xr[:,64:72,:] into dense (512,512) bf16 hi/lo -----------------
__global__ void gather_rows_kernel(const float* __restrict__ X2,
        ushort_t* __restrict__ RRH, ushort_t* __restrict__ RRL, int total) {
    int idx = blockIdx.x * 256 + threadIdx.x;
    if (idx >= total) return;
    int d = idx & 511;
    int row = idx >> 9;
    int g2 = row >> 3, rr = row & 7;
    float v = X2[((size_t)(g2 * 72 + 64 + rr)) * 512 + d];
    unsigned short h = f2bf(v);
    RRH[idx] = h;
    RRL[idx] = f2bf(v - bf2f(h));
}

// ---- l2-normalize each 128-half of each out row (l2n commutes w/ expand) --
__global__ __launch_bounds__(64) void norm_half_kernel(const float* __restrict__ IN,
        float* __restrict__ OUT) {
    int b = blockIdx.x; int lane = threadIdx.x;
    size_t base = (size_t)(b >> 1) * 256 + (size_t)(b & 1) * 128;
    float v0 = IN[base + lane], v1 = IN[base + 64 + lane];
    float ss = wave_sum64(v0 * v0 + v1 * v1);
    float sc = 1.0f / fmaxf(sqrtf(ss), 1e-12f);
    OUT[base + lane]      = v0 * sc;
    OUT[base + 64 + lane] = v1 * sc;
}

// ---- l2-normalize key columns: keys (32,128,16) over d --------------------
__global__ __launch_bounds__(64) void norm_keys_kernel(const float* __restrict__ Kin,
        float* __restrict__ Kout) {
    int b = blockIdx.x; int lane = threadIdx.x;
    int g = b >> 4, e = b & 15;
    size_t base = (size_t)g * 2048 + e;
    float v0 = Kin[base + (size_t)lane * 16];
    float v1 = Kin[base + (size_t)(lane + 64) * 16];
    float ss = wave_sum64(v0 * v0 + v1 * v1);
    float sc = 1.0f / fmaxf(sqrtf(ss), 1e-12f);
    Kout[base + (size_t)lane * 16]        = v0 * sc;
    Kout[base + (size_t)(lane + 64) * 16] = v1 * sc;
}

// ---- logits + top2 (stable, jax tie-break) --------------------------------
__global__ __launch_bounds__(64) void logits_top2_kernel(const float* __restrict__ OUTN,
        const float* __restrict__ KRN, const float* __restrict__ KGN,
        float* __restrict__ out) {
    int blk = blockIdx.x;
    int g = blk >> 6, bcol = blk & 63;
    int b = bcol >> 5, l = bcol & 31;
    int lsrc = (l + 31) & 31;     // roll(+1): element l comes from l-1
    int r = g >> 2;               // repeat RM=4
    int row = (b * 32 + lsrc) * 8 + r;
    const float* rvec = OUTN + (size_t)row * 256;
    __shared__ float sc[32];
    int lane = threadIdx.x;
    if (lane < 32) {
        int e = lane & 15;
        const float* kb = ((lane < 16) ? KRN : KGN) + (size_t)g * 2048 + e;
        const float* xv = (lane < 16) ? rvec : (rvec + 128);
        float s = 0.f;
#pragma unroll 8
        for (int d = 0; d < 128; ++d) s = fmaf(xv[d], kb[(size_t)d * 16], s);
        sc[lane] = s;
    }
    __syncthreads();
    if (lane == 0) {
        float bv = -1e30f, sv = -1e30f; int bi = 0, si = 0;
#pragma unroll
        for (int e = 0; e < 16; ++e) {
            float v = sc[e];
            if (v > bv) { sv = bv; si = bi; bv = v; bi = e; }
            else if (v > sv) { sv = v; si = e; }
        }
        size_t base = (size_t)g * 128 + (size_t)bcol * 2;
        out[base]            = bv;
        out[base + 1]        = sv;
        out[4096 + base]     = sc[16 + bi];
        out[4096 + base + 1] = sc[16 + si];
    }
}

// ---------------------------------------------------------------------------
static void run_layer(float* X, float* BIG, float* Qb, float* Kb, float* Vb,
                      ushort_t* XNH, ushort_t* XNL, ushort_t* AOH, ushort_t* AOL,
                      ushort_t* MIDH, ushort_t* MIDL,
                      const unsigned short* WH, const unsigned short* WL,
                      const float* n1, const float* n2,
                      const int* doc, int G, int Sg, hipStream_t stream) {
    const size_t oQKV = 0, oO = 786432, oUP = 1048576, oDN = 2097152;
    int T = G * Sg;
    rmsnorm_kernel<<<T, 256, 0, stream>>>(X, n1, XNH, XNL);
    gemm3<<<dim3(12, T / 128), 256, 0, stream>>>(XNH, XNL, WH + oQKV, WL + oQKV, nullptr, BIG, T, 1536, 512);
    int rp = T * 256;
    rope_pack_kernel<<<(rp + 255) / 256, 256, 0, stream>>>(BIG, Qb, Kb, Vb, Sg, rp);
    int qblocks = (Sg + 63) >> 6;
    if (doc)
        attn3_kernel<true><<<dim3(qblocks, G * 8), 256, 0, stream>>>(Qb, Kb, Vb, doc, AOH, AOL, Sg);
    else
        attn3_kernel<false><<<dim3(qblocks, G * 8), 256, 0, stream>>>(Qb, Kb, Vb, nullptr, AOH, AOL, Sg);
    gemm3<<<dim3(4, T / 128), 256, 0, stream>>>(AOH, AOL, WH + oO, WL + oO, X, X, T, 512, 512);
    rmsnorm_kernel<<<T, 256, 0, stream>>>(X, n2, XNH, XNL);
    gemm3<<<dim3(16, T / 128), 256, 0, stream>>>(XNH, XNL, WH + oUP, WL + oUP, nullptr, BIG, T, 2048, 512);
    silu_mul_kernel<<<(T * 1024 + 255) / 256, 256, 0, stream>>>(BIG, MIDH, MIDL, T * 1024);
    gemm3<<<dim3(4, T / 128), 256, 0, stream>>>(MIDH, MIDL, WH + oDN, WL + oDN, X, X, T, 512, 1024);
}

static void split_layer(const float* qkv, const float* o, const float* up, const float* dn,
                        unsigned short* WH, unsigned short* WL, hipStream_t stream) {
    const size_t oQKV = 0, oO = 786432, oUP = 1048576, oDN = 2097152;
    wsplit_kernel<<<dim3(48, 16), 256, 0, stream>>>(qkv, WH + oQKV, WL + oQKV, 512, 1536);
    wsplit_kernel<<<dim3(16, 16), 256, 0, stream>>>(o,   WH + oO,   WL + oO,   512, 512);
    wsplit_kernel<<<dim3(64, 16), 256, 0, stream>>>(up,  WH + oUP,  WL + oUP,  512, 2048);
    wsplit_kernel<<<dim3(16, 32), 256, 0, stream>>>(dn,  WH + oDN,  WL + oDN,  1024, 512);
}

extern "C" void kernel_launch(void* const* d_in, const int* in_sizes, int n_in,
                              void* d_out, int out_size, void* d_ws, size_t ws_size,
                              hipStream_t stream) {
    const float* x_in    = (const float*)d_in[0];
    const int*   doc     = (const int*)d_in[1];
    const float* rt      = (const float*)d_in[2];
    const float* out_w   = (const float*)d_in[3];
    const float* k_rt    = (const float*)d_in[4];
    const float* k_gt    = (const float*)d_in[5];
    const float* enc_qkv = (const float*)d_in[6];
    const float* enc_o   = (const float*)d_in[7];
    const float* enc_up  = (const float*)d_in[8];
    const float* enc_dn  = (const float*)d_in[9];
    const float* enc_n1  = (const float*)d_in[10];
    const float* enc_n2  = (const float*)d_in[11];
    const float* rtr_qkv = (const float*)d_in[12];
    const float* rtr_o   = (const float*)d_in[13];
    const float* rtr_up  = (const float*)d_in[14];
    const float* rtr_dn  = (const float*)d_in[15];
    const float* rtr_n1  = (const float*)d_in[16];
    const float* rtr_n2  = (const float*)d_in[17];

    float* ws = (float*)d_ws;
    size_t off = 0;
    auto alloc = [&](size_t n) { float* p = ws + off; off += n; return p; };
    float* X    = alloc(4608UL * 512);
    float* X2   = alloc(4608UL * 512);
    float* BIG  = alloc(4608UL * 2048);
    float* Qb   = alloc(4608UL * 512);
    float* Kb   = alloc(4608UL * 512);
    float* Vb   = alloc(4608UL * 512);
    unsigned short* WH = (unsigned short*)(ws + off);
    unsigned short* WL = WH + 2621440UL;
    off += 2621440UL;
    // ---- dead-range aliases (stream-ordered, non-overlapping lifetimes) ----
    ushort_t* XNH = (ushort_t*)Qb;             // XN live rms->gemm
    ushort_t* XNL = XNH + 4608UL * 512;
    ushort_t* MIDH = (ushort_t*)Qb;            // MID spans Qb+Kb (T x 1024 x2B each)
    ushort_t* MIDL = (ushort_t*)Kb;
    ushort_t* AOH = (ushort_t*)BIG;            // AO in BIG (dead rope->up-gemm)
    ushort_t* AOL = AOH + 4608UL * 512;
    ushort_t* RRH = (ushort_t*)X;              // X dead after router_build
    ushort_t* RRL = RRH + 262144;
    float* OUTM = X + 262144;
    float* OUTN = X + 393216;
    float* KRN  = X + 524288;
    float* KGN  = X + 589824;
    (void)ws_size; (void)in_sizes; (void)n_in; (void)out_size;

    copy_in_kernel<<<(2097152 + 255) / 256, 256, 0, stream>>>(x_in, X, 2097152);

    for (int i = 0; i < 4; ++i) {
        split_layer(enc_qkv + (size_t)i * 512 * 1536,
                    enc_o   + (size_t)i * 512 * 512,
                    enc_up  + (size_t)i * 512 * 2048,
                    enc_dn  + (size_t)i * 1024 * 512, WH, WL, stream);
        run_layer(X, BIG, Qb, Kb, Vb, XNH, XNL, AOH, AOL, MIDH, MIDL, WH, WL,
                  enc_n1 + (size_t)i * 512, enc_n2 + (size_t)i * 512,
                  doc, 2, 2048, stream);
    }

    int rb_total = 64 * 72 * 512;
    router_build_kernel<<<(rb_total + 255) / 256, 256, 0, stream>>>(X, rt, X2, rb_total);

    for (int i = 0; i < 2; ++i) {
        split_layer(rtr_qkv + (size_t)i * 512 * 1536,
                    rtr_o   + (size_t)i * 512 * 512,
                    rtr_up  + (size_t)i * 512 * 2048,
                    rtr_dn  + (size_t)i * 1024 * 512, WH, WL, stream);
        run_layer(X2, BIG, Qb, Kb, Vb, XNH, XNL, AOH, AOL, MIDH, MIDL, WH, WL,
                  rtr_n1 + (size_t)i * 512, rtr_n2 + (size_t)i * 512,
                  nullptr, 64, 72, stream);
    }

    gather_rows_kernel<<<(512 * 512) / 256, 256, 0, stream>>>(X2, RRH, RRL, 512 * 512);
    wsplit_kernel<<<dim3(8, 16), 256, 0, stream>>>(out_w, WH, WL, 512, 256);
    gemm3<<<dim3(2, 4), 256, 0, stream>>>(RRH, RRL, WH, WL, nullptr, OUTM, 512, 256, 512);

    norm_half_kernel<<<1024, 64, 0, stream>>>(OUTM, OUTN);
    norm_keys_kernel<<<512, 64, 0, stream>>>(k_rt, KRN);
    norm_keys_kernel<<<512, 64, 0, stream>>>(k_gt, KGN);
    logits_top2_kernel<<<2048, 64, 0, stream>>>(OUTN, KRN, KGN, (float*)d_out);
}